// Round 7
// baseline (491.228 us; speedup 1.0000x reference)
//
#include <hip/hip_runtime.h>
#include <hip/hip_bf16.h>
#include <math.h>

// HebbianPlasticLayer: B=DIN=DOUT=4096, fp32 in/out.
// out = y + eta*tanh(y)*s,  y = x@W.T + bias,  s = (x*x/||x||)@sigmoid(alpha).T
// Round 7: R6 fused dual-GEMM (Y bf16 / S fp8) with fp8 LDS reads upgraded to
// ds_read_b128 covering both K-halves. fp8 global layout is chunk-permuted
// within each 64-elem K-block (chunk c at position (c&3)*2 + (c>>2)) so the
// s=0/s=1 chunks (g, g^4) are adjacent 16B -> conflict-free b128 reads
// (R6's b64 reads had a structural 4-way conflict at 64B row stride).
// Row norm folded into p8 at conversion (no sumsq/memset/atomics).

typedef __attribute__((ext_vector_type(4))) float floatx4;
typedef __attribute__((ext_vector_type(8))) short shortx8;
typedef __attribute__((ext_vector_type(2))) long longx2;

#define MAT_N 4096
#define MAT_ELEMS ((size_t)MAT_N * MAT_N)

__device__ __forceinline__ unsigned short f2bf(float f) {
    unsigned int u = __float_as_uint(f);
    unsigned int r = (u + 0x7fffu + ((u >> 16) & 1u)) >> 16;   // RNE
    return (unsigned short)r;
}

__device__ __forceinline__ int pack_fp8x4(float a, float b, float c, float d) {
    int p = __builtin_amdgcn_cvt_pk_fp8_f32(a, b, 0, false);
    return __builtin_amdgcn_cvt_pk_fp8_f32(c, d, p, true);
}

__device__ __forceinline__ void gload_lds16(const void* gptr, void* lptr) {
    __builtin_amdgcn_global_load_lds(
        (const __attribute__((address_space(1))) unsigned int*)gptr,
        (__attribute__((address_space(3))) unsigned int*)lptr,
        16, 0, 0);
}

// chunk permutation within a 64-elem K-block: chunk c -> position (c&3)*2 + (c>>2)
__device__ __forceinline__ int perm8(int c) { return ((c & 3) << 1) | (c >> 2); }

// ---------- conv x (block per row): xb = bf16(x), p8 = fp8(x^2/(||x||+1e-8)) ----------
__global__ __launch_bounds__(256) void convx_kernel(const float* __restrict__ x,
                                                    unsigned short* __restrict__ xb,
                                                    unsigned char* __restrict__ p8) {
    const int row = blockIdx.x;
    const int t = threadIdx.x;
    const float* xr = x + (size_t)row * MAT_N;
    // thread handles chunks t and t+256 (8 consecutive elems each)
    float v[2][8];
    float s = 0.f;
#pragma unroll
    for (int h = 0; h < 2; h++) {
        const float4* p = (const float4*)(xr + (t + h * 256) * 8);
        float4 a = p[0], b = p[1];
        v[h][0] = a.x; v[h][1] = a.y; v[h][2] = a.z; v[h][3] = a.w;
        v[h][4] = b.x; v[h][5] = b.y; v[h][6] = b.z; v[h][7] = b.w;
#pragma unroll
        for (int j = 0; j < 8; j++) s += v[h][j] * v[h][j];
    }
    for (int off = 32; off > 0; off >>= 1) s += __shfl_down(s, off, 64);
    __shared__ float red[4];
    if ((t & 63) == 0) red[t >> 6] = s;
    __syncthreads();
    const float inv = 1.0f / (sqrtf(red[0] + red[1] + red[2] + red[3]) + 1e-8f);
    unsigned short* xrow = xb + (size_t)row * MAT_N;
    unsigned char* prow = p8 + (size_t)row * MAT_N;
#pragma unroll
    for (int h = 0; h < 2; h++) {
        const int c = t + h * 256;                 // chunk index in row (0..511)
        shortx8 xo;
        float q[8];
#pragma unroll
        for (int j = 0; j < 8; j++) {
            xo[j] = (short)f2bf(v[h][j]);
            q[j] = v[h][j] * v[h][j] * inv;
        }
        *(shortx8*)(xrow + c * 8) = xo;
        int2 pv = {pack_fp8x4(q[0], q[1], q[2], q[3]),
                   pack_fp8x4(q[4], q[5], q[6], q[7])};
        // permuted position within the 64-elem K-block
        *(int2*)(prow + (c & ~7) * 8 + perm8(c & 7) * 8) = pv;
    }
}

// ---------- conv W,alpha: wb = bf16(W), a8 = fp8(sigmoid(alpha)) permuted ----------
__global__ __launch_bounds__(512) void convwa_kernel(const float* __restrict__ W,
                                                     const float* __restrict__ alpha,
                                                     unsigned short* __restrict__ wb,
                                                     unsigned char* __restrict__ a8) {
    const size_t c = (size_t)blockIdx.x * 512 + threadIdx.x;   // global chunk idx
    const size_t base = c * 8;
    const float4* wp = (const float4*)(W + base);
    const float4* ap = (const float4*)(alpha + base);
    float4 w0 = wp[0], w1 = wp[1], a0 = ap[0], a1 = ap[1];
    float wv[8] = {w0.x, w0.y, w0.z, w0.w, w1.x, w1.y, w1.z, w1.w};
    float av[8] = {a0.x, a0.y, a0.z, a0.w, a1.x, a1.y, a1.z, a1.w};
    shortx8 wo;
    float sg[8];
#pragma unroll
    for (int j = 0; j < 8; j++) {
        wo[j] = (short)f2bf(wv[j]);
        sg[j] = 1.0f / (1.0f + __expf(-av[j]));
    }
    *(shortx8*)(wb + base) = wo;
    int2 pv = {pack_fp8x4(sg[0], sg[1], sg[2], sg[3]),
               pack_fp8x4(sg[4], sg[5], sg[6], sg[7])};
    *(int2*)(a8 + (base & ~(size_t)63) + perm8((int)(c & 7)) * 8) = pv;
}

// ---------- fused dual-GEMM: Y bf16 + S fp8, 512 threads, BK=64 ----------
// bf16 LDS: rows 128B, 16B-chunk fetch-swizzle kc' = kc ^ (row&7) (0 conflicts).
// fp8 LDS: rows 64B, plain layout; b128 read at row*64 + quad*16 yields both
// K-half frags (global layout pre-permuted) -- stride-1-b128 bank pattern.
__global__ __launch_bounds__(512, 4) void fused_gemm_kernel(
    const unsigned short* __restrict__ X,
    const unsigned short* __restrict__ Wb,
    const unsigned char* __restrict__ P8,
    const unsigned char* __restrict__ A8,
    const float* __restrict__ bias,
    const float* __restrict__ eta_p,
    float* __restrict__ out) {
    constexpr int K = MAT_N;
    constexpr int N = MAT_N;
    __shared__ __align__(16) unsigned short sX[128 * 64];   // 16 KB
    __shared__ __align__(16) unsigned short sW[128 * 64];   // 16 KB
    __shared__ __align__(16) unsigned char  sP[128 * 64];   // 8 KB
    __shared__ __align__(16) unsigned char  sA[128 * 64];   // 8 KB

    const int tid = threadIdx.x;
    const int row0 = blockIdx.y * 128;
    const int col0 = blockIdx.x * 128;
    const int lane = tid & 63;
    const int wave = tid >> 6;           // 0..7
    const int wm = (wave >> 1) * 32;     // 4x2 wave grid: 32-row x 64-col
    const int wn = (wave & 1) * 64;
    const int quad = lane >> 4;
    const int l16 = lane & 15;

    floatx4 accY[2][4], accS[2][4];
#pragma unroll
    for (int i = 0; i < 2; i++)
#pragma unroll
        for (int j = 0; j < 4; j++) {
            accY[i][j] = (floatx4){0.f, 0.f, 0.f, 0.f};
            accS[i][j] = (floatx4){0.f, 0.f, 0.f, 0.f};
        }

    // bf16 staging: thread t -> row_s = t>>3 (0..63), chunk (t&7)^(row&7), 2 issues
    const int row_s = tid >> 3;
    const int kc_g  = (tid & 7) ^ (row_s & 7);
    const size_t arow = (size_t)(row0 + row_s) * K + kc_g * 8;
    const size_t brow = (size_t)(col0 + row_s) * K + kc_g * 8;
    // fp8 staging: thread t -> row r8 = t>>2 (0..127), 16B position t&3, 1 issue
    const int r8 = tid >> 2;
    const size_t prow = (size_t)(row0 + r8) * K + (tid & 3) * 16;
    const size_t qrow = (size_t)(col0 + r8) * K + (tid & 3) * 16;

    for (int k0 = 0; k0 < K; k0 += 64) {
#pragma unroll
        for (int i = 0; i < 2; i++) {
            const size_t go = (size_t)i * 64 * K + k0;
            const int lo = i * 4096 + tid * 8;
            gload_lds16(X + arow + go, sX + lo);
            gload_lds16(Wb + brow + go, sW + lo);
        }
        gload_lds16(P8 + prow + k0, sP + tid * 16);
        gload_lds16(A8 + qrow + k0, sA + tid * 16);
        __syncthreads();

        // ---- fp8 GEMM: one b128 per frag-pair covers both K-halves ----
        {
            longx2 apv[2], bpv[4];
#pragma unroll
            for (int i = 0; i < 2; i++)
                apv[i] = *(const longx2*)(sP + (wm + i * 16 + l16) * 64 + quad * 16);
#pragma unroll
            for (int j = 0; j < 4; j++)
                bpv[j] = *(const longx2*)(sA + (wn + j * 16 + l16) * 64 + quad * 16);
#pragma unroll
            for (int s = 0; s < 2; s++)
#pragma unroll
                for (int i = 0; i < 2; i++)
#pragma unroll
                    for (int j = 0; j < 4; j++)
                        accS[i][j] = __builtin_amdgcn_mfma_f32_16x16x32_fp8_fp8(
                            apv[i][s], bpv[j][s], accS[i][j], 0, 0, 0);
        }
        // ---- bf16 GEMM ----
#pragma unroll
        for (int s = 0; s < 2; s++) {
            const int kcp = ((s * 4 + quad) ^ (l16 & 7)) * 8;
            shortx8 af[2], bfr[4];
#pragma unroll
            for (int i = 0; i < 2; i++)
                af[i] = *(const shortx8*)(sX + (wm + i * 16 + l16) * 64 + kcp);
#pragma unroll
            for (int j = 0; j < 4; j++)
                bfr[j] = *(const shortx8*)(sW + (wn + j * 16 + l16) * 64 + kcp);
#pragma unroll
            for (int i = 0; i < 2; i++)
#pragma unroll
                for (int j = 0; j < 4; j++)
                    accY[i][j] = __builtin_amdgcn_mfma_f32_16x16x32_bf16(af[i], bfr[j], accY[i][j], 0, 0, 0);
        }
        __syncthreads();
    }

    const float eta = *eta_p;
#pragma unroll
    for (int i = 0; i < 2; i++) {
#pragma unroll
        for (int r = 0; r < 4; r++) {
            const int grow = row0 + wm + i * 16 + quad * 4 + r;
#pragma unroll
            for (int j = 0; j < 4; j++) {
                // C/D layout: row = quad*4 + r, col = lane&15   [m89/m91 verified]
                const int gcol = col0 + wn + j * 16 + l16;
                float y = accY[i][j][r] + bias[gcol];
                out[(size_t)grow * N + gcol] = y + eta * tanhf(y) * accS[i][j][r];
            }
        }
    }
}

extern "C" void kernel_launch(void* const* d_in, const int* in_sizes, int n_in,
                              void* d_out, int out_size, void* d_ws, size_t ws_size,
                              hipStream_t stream) {
    const float* x     = (const float*)d_in[0];
    const float* W     = (const float*)d_in[1];
    const float* alpha = (const float*)d_in[2];
    const float* eta   = (const float*)d_in[3];
    const float* bias  = (const float*)d_in[4];
    float* out = (float*)d_out;

    // ws: xb 32MB | wb 32MB | p8 16MB | a8 16MB
    unsigned short* xb = (unsigned short*)d_ws;
    unsigned short* wb = xb + MAT_ELEMS;
    unsigned char*  p8 = (unsigned char*)(wb + MAT_ELEMS);
    unsigned char*  a8 = p8 + MAT_ELEMS;

    convx_kernel<<<MAT_N, 256, 0, stream>>>(x, xb, p8);
    convwa_kernel<<<MAT_ELEMS / (8 * 512), 512, 0, stream>>>(W, alpha, wb, a8);

    dim3 grid(MAT_N / 128, MAT_N / 128);
    fused_gemm_kernel<<<grid, 512, 0, stream>>>(xb, wb, p8, a8, bias, eta, out);
}